// Round 18
// baseline (317.814 us; speedup 1.0000x reference)
//
#include <hip/hip_runtime.h>
#include <hip/hip_bf16.h>
#include <cstdint>
#include <cstddef>

#define EMBED 1024
#define SLEN  2048
#define NB    2
#define HEADS 16
#define HDIM  64
#define FFDIM 4096
#define ROWS  (NB * SLEN)   // 4096
#define LOG2E 1.4426950408889634f

typedef __attribute__((ext_vector_type(8))) __bf16 bf16x8;
typedef __attribute__((ext_vector_type(4))) __bf16 bf16x4;
typedef __attribute__((ext_vector_type(4))) float  f32x4;
typedef __attribute__((ext_vector_type(4))) _Float16 f16x4;

__device__ __forceinline__ void gload_lds16(const void* g, void* l) {
  __builtin_amdgcn_global_load_lds(
      (const __attribute__((address_space(1))) void*)g,
      (__attribute__((address_space(3))) void*)l, 16, 0, 0);
}

#define SCHED() __builtin_amdgcn_sched_barrier(0)
#define BAR()                              \
  do {                                     \
    __builtin_amdgcn_s_barrier();          \
    __builtin_amdgcn_sched_barrier(0);     \
  } while (0)
#define WAITVM(N)                                           \
  do {                                                      \
    asm volatile("s_waitcnt vmcnt(" #N ")" ::: "memory");   \
  } while (0)
#define WAITLGKM(N)                                         \
  do {                                                      \
    asm volatile("s_waitcnt lgkmcnt(" #N ")" ::: "memory"); \
  } while (0)

// ---- fused prologue: weight transposes (b<3072) + x cast (3072..4095) +
//      mask tile flags (4096..5119), one dispatch ----
__global__ __launch_bounds__(256) void prologue_k(
    const float* __restrict__ x, const int* __restrict__ mask,
    const float* __restrict__ Wq, const float* __restrict__ Wk,
    const float* __restrict__ Wv, const float* __restrict__ Wo,
    const float* __restrict__ W1, const float* __restrict__ W2,
    __bf16* __restrict__ xb, int* __restrict__ flags,
    __bf16* __restrict__ Wqt, __bf16* __restrict__ Wkt, __bf16* __restrict__ Wvt,
    __bf16* __restrict__ Wot, __bf16* __restrict__ W1t, __bf16* __restrict__ W2t) {
  const int b = blockIdx.x;
  const int tid = threadIdx.x;
  if (b < 3072) {  // ---- transpose+cast: in[R][C] f32 -> out[C][R] bf16 ----
    __shared__ float t[64][65];
    const float* src;
    __bf16* dst;
    int R, C, tile;
    if (b < 1024) {
      const int w = b >> 8;
      tile = b & 255; R = 1024; C = 1024;
      src = (w == 0) ? Wq : (w == 1) ? Wk : (w == 2) ? Wv : Wo;
      dst = (w == 0) ? Wqt : (w == 1) ? Wkt : (w == 2) ? Wvt : Wot;
    } else if (b < 2048) {
      tile = b - 1024; R = 1024; C = 4096; src = W1; dst = W1t;
    } else {
      tile = b - 2048; R = 4096; C = 1024; src = W2; dst = W2t;
    }
    const int ct = C >> 6;
    const int tr = (tile / ct) * 64, tc = (tile % ct) * 64;
    const int tx = tid & 63;
    const int ty = tid >> 6;
#pragma unroll
    for (int i = 0; i < 16; ++i) {
      int a = ty * 16 + i;
      t[a][tx] = src[(size_t)(tr + a) * C + tc + tx];
    }
    __syncthreads();
#pragma unroll
    for (int i = 0; i < 16; ++i) {
      int bb = ty * 16 + i;
      dst[(size_t)(tc + bb) * R + tr + tx] = (__bf16)t[tx][bb];
    }
  } else if (b < 4096) {  // ---- cast x: f32 -> bf16, 1024 float4/block ----
    const int base = (b - 3072) * 1024;
#pragma unroll
    for (int it = 0; it < 4; ++it) {
      const int i = base + it * 256 + tid;
      float4 v = ((const float4*)x)[i];
      bf16x4 o;
      o.x = (__bf16)v.x; o.y = (__bf16)v.y; o.z = (__bf16)v.z; o.w = (__bf16)v.w;
      ((bf16x4*)xb)[i] = o;
    }
  } else {  // ---- mask flags: 1 iff all mask!=0 in 128q x 64k tile ----
    const int mb = b - 4096;
    const int kt = mb & 31, qt = (mb >> 5) & 15, n = mb >> 9;
    const int* base = mask + ((size_t)n * SLEN + qt * 128) * SLEN + kt * 64;
    const int rw = tid >> 4;
    const int cg = tid & 15;
    int ok = 1;
#pragma unroll
    for (int i = 0; i < 8; ++i) {
      int4 v = ((const int4*)(base + (size_t)(rw + i * 16) * SLEN))[cg];
      ok &= (v.x != 0) & (v.y != 0) & (v.z != 0) & (v.w != 0);
    }
    __shared__ int red;
    if (tid == 0) red = 1;
    __syncthreads();
    if (!ok) red = 0;  // benign race: all writers store 0
    __syncthreads();
    if (tid == 0) flags[mb] = red;
  }
}

// ====== 256x256-tile GEMM, 1024 threads = 16 waves (4M x 4N), depth-4 ======
// Per wave: 64x64 output (acc[4][4]), 8 ds_reads + 16 MFMA per K-tile.
// 4 waves/SIMD for latency hiding. Counted vmcnt (steady 4), one barrier/iter.
// MODE 3: bf16 relu; MODE 4: fused QKV; MODE 5: split-K f16 partials.
template <int MODE>
__global__ __launch_bounds__(1024, 1) void gemm256(
    const __bf16* __restrict__ A, const __bf16* __restrict__ Bt,
    const float* __restrict__ bias, const float* __restrict__ bias2,
    const float* __restrict__ bias3,
    void* __restrict__ outp, void* __restrict__ outp2, void* __restrict__ outp3,
    int M, int N, int K, int Kc, float oscale) {
  __shared__ __align__(16) char smem[131072];  // 4 x 32KB staging; epilogue aliases
  const int tid = threadIdx.x;
  const int lane = tid & 63;
  const int ntile = N >> 8;
  const int mt = M >> 8;
  const int cpx = gridDim.x >> 3;
  int u = (blockIdx.x & 7) * cpx + (blockIdx.x >> 3);  // XCD-chunked
  int kz = 0;
  if constexpr (MODE == 5) {
    const int tiles = mt * ntile;
    kz = u / tiles;
    u -= kz * tiles;
  }
  int bm, bn;
  {  // group-of-4 rasterization
    const int G = (ntile >= 4) ? 4 : ntile;
    const int gsz = mt * G;
    const int g = u / gsz;
    const int rem = u - g * gsz;
    bm = rem / G;
    bn = g * G + rem % G;
  }
  const int trow = bm << 8, tcol = bn << 8;

  // staging: thread (r0 = tid&255, c0 = tid>>8); 1 load covers each 16KB half
  const int r0 = tid & 255;
  const int c0 = tid >> 8;  // 0..3 (kchunk)
  const __bf16* Ag = A + (size_t)(trow + r0) * K + (size_t)kz * Kc + c0 * 8;
  const __bf16* Bg = Bt + (size_t)(tcol + r0) * K + (size_t)kz * Kc + c0 * 8;

  auto stage = [&](int buf, int kt) {
    char* la = smem + buf * 32768 + tid * 16;
    char* lb = la + 16384;
    gload_lds16(Ag + (size_t)kt * 32, la);
    gload_lds16(Bg + (size_t)kt * 32, lb);
  };

  const int wave = tid >> 6;   // 0..15
  const int wr = wave >> 2;    // 0..3: 64-row band
  const int wc = wave & 3;     // 0..3: 64-col band
  const int l16 = lane & 15;
  const int g4 = lane >> 4;

  f32x4 acc[4][4];
#pragma unroll
  for (int i = 0; i < 4; ++i)
#pragma unroll
    for (int j = 0; j < 4; ++j) acc[i][j] = (f32x4)0.0f;

  const int nk = Kc >> 5;
  stage(0, 0);
  stage(1, 1);
  stage(2, 2);
  WAITVM(4);  // tile 0's 2 loads landed; tiles 1,2 (4 loads) in flight
  BAR();
  for (int kt = 0; kt < nk; ++kt) {
    const int cur = kt & 3;
    const char* base = smem + cur * 32768;
    bf16x8 af[4], bfr[4];
#pragma unroll
    for (int i = 0; i < 4; ++i) {
      af[i]  = *(const bf16x8*)(base + g4 * 4096 + (wr * 64 + i * 16 + l16) * 16);
      bfr[i] = *(const bf16x8*)(base + 16384 + g4 * 4096 + (wc * 64 + i * 16 + l16) * 16);
    }
    if (kt + 3 < nk) stage((kt + 3) & 3, kt + 3);  // buffer last read in iter kt-1
    SCHED();
    WAITLGKM(0);
    SCHED();
    __builtin_amdgcn_s_setprio(1);
#pragma unroll
    for (int mi = 0; mi < 4; ++mi)
#pragma unroll
      for (int ni = 0; ni < 4; ++ni)
        acc[mi][ni] =
            __builtin_amdgcn_mfma_f32_16x16x32_bf16(af[mi], bfr[ni], acc[mi][ni], 0, 0, 0);
    __builtin_amdgcn_s_setprio(0);
    if (kt + 3 < nk) {
      WAITVM(4);   // tile kt+1's loads landed (own); barrier extends to all waves
    } else if (kt + 3 == nk) {
      WAITVM(2);
    } else if (kt + 2 == nk) {
      WAITVM(0);
    }
    BAR();
  }

  if constexpr (MODE == 5) {
#pragma unroll
    for (int mi = 0; mi < 4; ++mi)
#pragma unroll
      for (int ni = 0; ni < 4; ++ni) {
        const int col = tcol + wc * 64 + ni * 16 + l16;
#pragma unroll
        for (int r = 0; r < 4; ++r) {
          const int row = trow + wr * 64 + mi * 16 + g4 * 4 + r;
          ((_Float16*)outp)[(size_t)kz * M * N + (size_t)row * N + col] =
              (_Float16)acc[mi][ni][r];
        }
      }
  } else {
    const int sel = (MODE == 4) ? (tcol >> 10) : 0;
    const float* bp = (MODE == 4) ? (sel == 0 ? bias : sel == 1 ? bias2 : bias3) : bias;
    const int cc0 = (MODE == 4) ? (tcol & 1023) : tcol;
    const int n = trow >> 11;
    if (MODE == 4 && sel == 2) {
      // Vt: transposed repack [col 256][row 136 pad] per 128-row half
      __bf16(*repT)[136] = (__bf16(*)[136])smem;
#pragma unroll
      for (int h = 0; h < 2; ++h) {
        __syncthreads();
        if ((wr >> 1) == h) {
          const int rbase = (wr & 1) * 64;
#pragma unroll
          for (int mi = 0; mi < 4; ++mi)
#pragma unroll
            for (int ni = 0; ni < 4; ++ni) {
              const int cl = wc * 64 + ni * 16 + l16;
              const float bcol = bp[cc0 + cl];
#pragma unroll
              for (int r = 0; r < 4; ++r)
                repT[cl][rbase + mi * 16 + g4 * 4 + r] = (__bf16)(acc[mi][ni][r] + bcol);
            }
        }
        __syncthreads();
#pragma unroll
        for (int it = 0; it < 4; ++it) {
          const int cidx = it * 1024 + tid;
          const int cl = cidx >> 4, seg = cidx & 15;
          const int col = cc0 + cl, hh = col >> 6, dd = col & 63;
          *(bf16x8*)((__bf16*)outp3 + ((size_t)((n * HEADS + hh) * HDIM) + dd) * SLEN +
                     (trow & 2047) + h * 128 + seg * 8) = *(const bf16x8*)&repT[cl][seg * 8];
        }
      }
    } else {
      __bf16(*rep)[264] = (__bf16(*)[264])smem;
#pragma unroll
      for (int h = 0; h < 2; ++h) {
        __syncthreads();
        if ((wr >> 1) == h) {
          const int rbase = (wr & 1) * 64;
#pragma unroll
          for (int mi = 0; mi < 4; ++mi)
#pragma unroll
            for (int ni = 0; ni < 4; ++ni) {
              const int cl = wc * 64 + ni * 16 + l16;
              float bcol = bp[cc0 + cl];
#pragma unroll
              for (int r = 0; r < 4; ++r) {
                float v = acc[mi][ni][r] + bcol;
                if constexpr (MODE == 4) {
                  if (sel == 0) v *= oscale;
                } else {
                  v = fmaxf(v, 0.0f);
                }
                rep[rbase + mi * 16 + g4 * 4 + r][cl] = (__bf16)v;
              }
            }
        }
        __syncthreads();
        if constexpr (MODE == 3) {
#pragma unroll
          for (int it = 0; it < 4; ++it) {
            const int cidx = it * 1024 + tid;
            const int rl = cidx >> 5, seg = cidx & 31;
            *(bf16x8*)((__bf16*)outp + (size_t)(trow + h * 128 + rl) * N + tcol + seg * 8) =
                *(const bf16x8*)&rep[rl][seg * 8];
          }
        } else {
          __bf16* dst = (sel == 0) ? (__bf16*)outp : (__bf16*)outp2;
#pragma unroll
          for (int it = 0; it < 4; ++it) {
            const int cidx = it * 1024 + tid;
            const int rl = cidx >> 5, seg = cidx & 31;
            const int col = cc0 + seg * 8, hh = col >> 6, d = col & 63;
            const int s = (trow & 2047) + h * 128 + rl;
            *(bf16x8*)(dst + ((size_t)((n * HEADS + hh) * SLEN) + s) * HDIM + d) =
                *(const bf16x8*)&rep[rl][seg * 8];
          }
        }
      }
    }
  }
}

// ---------------- 128^2 GEMM (Wo split-K, f16 partials), depth-4 fine ----------------
__global__ __launch_bounds__(256, 2) void gemm_bt5(
    const __bf16* __restrict__ A, const __bf16* __restrict__ Bt,
    _Float16* __restrict__ outp, int M, int N, int K, int Kc) {
  __shared__ __align__(16) char smem[65536];  // 4 x 16KB
  const int tid = threadIdx.x;
  const int lane = tid & 63;
  const int ntile = N >> 7;
  const int cpx = gridDim.x >> 3;
  int u = (blockIdx.x & 7) * cpx + (blockIdx.x >> 3);
  const int tiles = (M >> 7) * ntile;
  const int kz = u / tiles;
  u -= kz * tiles;
  const int bm = u / ntile;
  const int bn = u % ntile;
  const int trow = bm << 7;
  const int tcol = bn << 7;

  const int c0 = tid >> 7;
  const int r0 = tid & 127;
  const __bf16* Ag = A + (size_t)(trow + r0) * K + (size_t)kz * Kc + c0 * 8;
  const __bf16* Bg = Bt + (size_t)(tcol + r0) * K + (size_t)kz * Kc + c0 * 8;

  auto stage = [&](int buf, int kt) {
    const __bf16* a0 = Ag + (size_t)kt * 32;
    const __bf16* b0 = Bg + (size_t)kt * 32;
    char* la = smem + buf * 16384 + tid * 16;
    char* lb = la + 8192;
    gload_lds16(a0, la);
    gload_lds16(a0 + 16, la + 4096);
    gload_lds16(b0, lb);
    gload_lds16(b0 + 16, lb + 4096);
  };

  const int wave = tid >> 6;
  const int wr = (wave >> 1) * 64;
  const int wc = (wave & 1) * 64;
  const int l16 = lane & 15;
  const int g4 = lane >> 4;

  f32x4 acc[4][4];
#pragma unroll
  for (int i = 0; i < 4; ++i)
#pragma unroll
    for (int j = 0; j < 4; ++j) acc[i][j] = (f32x4)0.0f;

  const int nk = Kc >> 5;
  stage(0, 0);
  stage(1, 1);
  stage(2, 2);
  WAITVM(8);
  BAR();
  for (int kt = 0; kt < nk; ++kt) {
    const int cur = kt & 3;
    const char* base = smem + cur * 16384;
    bf16x8 af[4], bfr[4];
#pragma unroll
    for (int i = 0; i < 4; ++i) {
      af[i]  = *(const bf16x8*)(base + g4 * 2048 + (wr + i * 16 + l16) * 16);
      bfr[i] = *(const bf16x8*)(base + 8192 + g4 * 2048 + (wc + i * 16 + l16) * 16);
    }
    if (kt + 3 < nk) stage((kt + 3) & 3, kt + 3);
    SCHED();
    WAITLGKM(0);
    SCHED();
    __builtin_amdgcn_s_setprio(1);
#pragma unroll
    for (int mi = 0; mi < 4; ++mi)
#pragma unroll
      for (int ni = 0; ni < 4; ++ni)
        acc[mi][ni] =
            __builtin_amdgcn_mfma_f32_16x16x32_bf16(af[mi], bfr[ni], acc[mi][ni], 0, 0, 0);
    __builtin_amdgcn_s_setprio(0);
    if (kt + 3 < nk) {
      WAITVM(8);
    } else if (kt + 3 == nk) {
      WAITVM(4);
    } else if (kt + 2 == nk) {
      WAITVM(0);
    }
    BAR();
  }
#pragma unroll
  for (int mi = 0; mi < 4; ++mi)
#pragma unroll
    for (int ni = 0; ni < 4; ++ni) {
      const int col = tcol + wc + ni * 16 + l16;
#pragma unroll
      for (int r = 0; r < 4; ++r) {
        const int row = trow + wr + mi * 16 + g4 * 4 + r;
        outp[(size_t)kz * M * N + (size_t)row * N + col] = (_Float16)acc[mi][ni][r];
      }
    }
}

// ---------------- flash attention: 8 waves x 16 q, LDS-staged K/V ----------------
// 512 blocks XCD-chunked; LDS 50 KB -> 2 blocks/CU = 16 waves/CU.
__global__ __launch_bounds__(512, 2) void attn_k(const __bf16* __restrict__ Q,
                                                 const __bf16* __restrict__ K,
                                                 const __bf16* __restrict__ Vt,
                                                 const int* __restrict__ mask,
                                                 const int* __restrict__ flags,
                                                 __bf16* __restrict__ ctx) {
  const int tid = threadIdx.x, lane = tid & 63, wave = tid >> 6;  // wave 0..7
  const int l16 = lane & 15, g4 = lane >> 4;
  const int bid = blockIdx.x;
  const int lb = (bid & 7) * 64 + (bid >> 3);
  const int qt = lb & 15, h = (lb >> 4) & 15, n = lb >> 8;
  const int q0 = qt * 128 + wave * 16;
  const __bf16* Qh = Q + (size_t)(n * HEADS + h) * SLEN * HDIM;
  const __bf16* Kh = K + (size_t)(n * HEADS + h) * SLEN * HDIM;
  const __bf16* Vh = Vt + (size_t)(n * HEADS + h) * HDIM * SLEN;
  const int* Mh = mask + (size_t)n * SLEN * SLEN;
  const int* Fh = flags + (n * 16 + qt) * 32;

  __shared__ __bf16 KV[2][2][8][64][8];              // 32 KB
  __shared__ __align__(16) __bf16 P_lds[8][16][72];  // 18 KB

  const int srow = tid & 63;
  const int schunk = tid >> 6;  // 0..7
  const __bf16* Kg = Kh + (size_t)srow * HDIM + schunk * 8;
  const __bf16* Vg = Vh + (size_t)srow * SLEN + schunk * 8;
  auto stage = [&](int buf, int kb) {
    char* lk = (char*)&KV[buf][0][0][0][0] + tid * 16;
    char* lv = (char*)&KV[buf][1][0][0][0] + tid * 16;
    gload_lds16(Kg + (size_t)kb * 64 * HDIM, lk);
    gload_lds16(Vg + kb * 64, lv);
  };

  const unsigned long long fbits = __ballot(Fh[lane & 31] != 0);

  bf16x8 qf[2];
#pragma unroll
  for (int kd = 0; kd < 2; ++kd)
    qf[kd] = *(const bf16x8*)(Qh + (size_t)(q0 + l16) * HDIM + kd * 32 + g4 * 8);

  float m_ = -INFINITY, lsum = 0.0f;
  f32x4 o[4];
#pragma unroll
  for (int ni = 0; ni < 4; ++ni) o[ni] = (f32x4)0.0f;

  const int nt = SLEN / 64;
  stage(0, 0);
  stage(1, 1);
  WAITVM(2);  // tile 0's 2 loads landed; tile 1 in flight
  BAR();
  int cur = 0;
  for (int kt = 0; kt < nt; ++kt) {
    const int kbase = kt * 64;
    const bool full = (fbits >> kt) & 1ull;
    bf16x8 kf[4][2], vf[2][4];
#pragma unroll
    for (int ni = 0; ni < 4; ++ni) {
      kf[ni][0] = *(const bf16x8*)&KV[cur][0][g4][ni * 16 + l16][0];
      kf[ni][1] = *(const bf16x8*)&KV[cur][0][4 + g4][ni * 16 + l16][0];
    }
    SCHED();
#pragma unroll
    for (int kb = 0; kb < 2; ++kb)
#pragma unroll
      for (int ni = 0; ni < 4; ++ni)
        vf[kb][ni] = *(const bf16x8*)&KV[cur][1][kb * 4 + g4][ni * 16 + l16][0];
    SCHED();
    WAITLGKM(8);  // kf ready; vf latency hides under QK + softmax
    SCHED();
    f32x4 s[4];
#pragma unroll
    for (int ni = 0; ni < 4; ++ni) s[ni] = (f32x4)0.0f;
    __builtin_amdgcn_s_setprio(1);
#pragma unroll
    for (int ni = 0; ni < 4; ++ni) {
      s[ni] = __builtin_amdgcn_mfma_f32_16x16x32_bf16(kf[ni][0], qf[0], s[ni], 0, 0, 0);
      s[ni] = __builtin_amdgcn_mfma_f32_16x16x32_bf16(kf[ni][1], qf[1], s[ni], 0, 0, 0);
    }
    __builtin_amdgcn_s_setprio(0);
    if (!full) {
#pragma unroll
      for (int ni = 0; ni < 4; ++ni)
#pragma unroll
        for (int r = 0; r < 4; ++r) {
          const int mk = Mh[(size_t)(q0 + l16) * SLEN + kbase + ni * 16 + 4 * g4 + r];
          s[ni][r] = mk ? s[ni][r] : -INFINITY;
        }
    }
    float a = fmaxf(fmaxf(s[0][0], s[0][1]), fmaxf(s[0][2], s[0][3]));
    float b = fmaxf(fmaxf(s[1][0], s[1][1]), fmaxf(s[1][2], s[1][3]));
    float c = fmaxf(fmaxf(s[2][0], s[2][1]), fmaxf(s[2][2], s[2][3]));
    float d = fmaxf(fmaxf(s[3][0], s[3][1]), fmaxf(s[3][2], s[3][3]));
    const float pmax = fmaxf(fmaxf(a, b), fmaxf(c, d));
    if (!__all(pmax <= m_ + 8.0f)) {  // rescale (first tile + rare growth)
      float pm2 = fmaxf(m_, pmax);
      pm2 = fmaxf(pm2, __shfl_xor(pm2, 16));
      pm2 = fmaxf(pm2, __shfl_xor(pm2, 32));
      const float al = __builtin_amdgcn_exp2f(m_ - pm2);
      m_ = pm2;
      lsum *= al;
#pragma unroll
      for (int r = 0; r < 4; ++r) {
        const float ao = __shfl(al, 4 * g4 + r);
#pragma unroll
        for (int ni = 0; ni < 4; ++ni) o[ni][r] *= ao;
      }
    }
    float ls = 0.0f;
#pragma unroll
    for (int ni = 0; ni < 4; ++ni) {
      bf16x4 pk;
#pragma unroll
      for (int r = 0; r < 4; ++r) {
        const float p = __builtin_amdgcn_exp2f(s[ni][r] - m_);
        ls += p;
        pk[r] = (__bf16)p;
      }
      *(bf16x4*)&P_lds[wave][l16][ni * 16 + 4 * g4] = pk;
    }
    lsum += ls;
    bf16x8 pa[2];
#pragma unroll
    for (int kb = 0; kb < 2; ++kb)
      pa[kb] = *(const bf16x8*)&P_lds[wave][l16][kb * 32 + 8 * g4];
    SCHED();
    WAITLGKM(0);
    SCHED();
    __builtin_amdgcn_s_setprio(1);
#pragma unroll
    for (int kb = 0; kb < 2; ++kb)
#pragma unroll
      for (int ni = 0; ni < 4; ++ni)
        o[ni] = __builtin_amdgcn_mfma_f32_16x16x32_bf16(pa[kb], vf[kb][ni], o[ni], 0, 0, 0);
    __builtin_amdgcn_s_setprio(0);
    WAITVM(0);  // tile kt+1 (staged last iter) landed
    BAR();      // all waves done reading KV[cur] and past their vm-wait
    if (kt + 2 < nt) stage(cur, kt + 2);  // overwrite just-freed buffer
    cur ^= 1;
  }
  {
    float l = lsum;
    l += __shfl_xor(l, 16);
    l += __shfl_xor(l, 32);
    lsum = l;
  }
#pragma unroll
  for (int r = 0; r < 4; ++r) {
    const float inv = __builtin_amdgcn_rcpf(__shfl(lsum, 4 * g4 + r));
#pragma unroll
    for (int ni = 0; ni < 4; ++ni) {
      ctx[((size_t)(n * SLEN) + q0 + 4 * g4 + r) * EMBED + h * HDIM + ni * 16 + l16] =
          (__bf16)(o[ni][r] * inv);
    }
  }
}

// ------- fused split-K reduce (f16 partials) + bias + bf16 residual + LayerNorm -------
__global__ __launch_bounds__(256) void ln_fused_k(const _Float16* __restrict__ p, int nz,
                                                  const float* __restrict__ bias,
                                                  const __bf16* __restrict__ resb,
                                                  const float* __restrict__ gw,
                                                  const float* __restrict__ bw,
                                                  float* __restrict__ of,
                                                  __bf16* __restrict__ ob) {
  const int tid = threadIdx.x;
  const size_t row = blockIdx.x;
  float4 bb = ((const float4*)bias)[tid];
  bf16x4 rr = ((const bf16x4*)(resb + row * EMBED))[tid];
  float4 v;
  v.x = bb.x + (float)rr[0];
  v.y = bb.y + (float)rr[1];
  v.z = bb.z + (float)rr[2];
  v.w = bb.w + (float)rr[3];
  for (int z = 0; z < nz; ++z) {
    f16x4 pz = ((const f16x4*)(p + (size_t)z * ROWS * EMBED + row * EMBED))[tid];
    v.x += (float)pz[0]; v.y += (float)pz[1]; v.z += (float)pz[2]; v.w += (float)pz[3];
  }
  float s = v.x + v.y + v.z + v.w;
  float sq = v.x * v.x + v.y * v.y + v.z * v.z + v.w * v.w;
#pragma unroll
  for (int off = 1; off < 64; off <<= 1) {
    s += __shfl_xor(s, off);
    sq += __shfl_xor(sq, off);
  }
  __shared__ float red[8];
  if ((tid & 63) == 0) { red[tid >> 6] = s; red[4 + (tid >> 6)] = sq; }
  __syncthreads();
  s = red[0] + red[1] + red[2] + red[3];
  sq = red[4] + red[5] + red[6] + red[7];
  const float mean = s * (1.0f / EMBED);
  const float var = sq * (1.0f / EMBED) - mean * mean;
  const float rstd = rsqrtf(var + 1e-5f);
  float4 gv = ((const float4*)gw)[tid];
  float4 bv2 = ((const float4*)bw)[tid];
  float4 ov;
  ov.x = (v.x - mean) * rstd * gv.x + bv2.x;
  ov.y = (v.y - mean) * rstd * gv.y + bv2.y;
  ov.z = (v.z - mean) * rstd * gv.z + bv2.z;
  ov.w = (v.w - mean) * rstd * gv.w + bv2.w;
  if (of) ((float4*)(of + row * EMBED))[tid] = ov;
  if (ob) {
    bf16x4 oh;
    oh.x = (__bf16)ov.x; oh.y = (__bf16)ov.y; oh.z = (__bf16)ov.z; oh.w = (__bf16)ov.w;
    ((bf16x4*)(ob + row * EMBED))[tid] = oh;
  }
}

extern "C" void kernel_launch(void* const* d_in, const int* in_sizes, int n_in,
                              void* d_out, int out_size, void* d_ws, size_t ws_size,
                              hipStream_t stream) {
  (void)in_sizes; (void)n_in; (void)out_size;
  const float* x   = (const float*)d_in[0];
  const int*  mask = (const int*)d_in[1];
  const float* Wq = (const float*)d_in[2];  const float* bq  = (const float*)d_in[3];
  const float* Wk = (const float*)d_in[4];  const float* bk  = (const float*)d_in[5];
  const float* Wv = (const float*)d_in[6];  const float* bv  = (const float*)d_in[7];
  const float* Wo = (const float*)d_in[8];  const float* bo  = (const float*)d_in[9];
  const float* g1 = (const float*)d_in[10]; const float* be1 = (const float*)d_in[11];
  const float* g2 = (const float*)d_in[12]; const float* be2 = (const float*)d_in[13];
  const float* W1 = (const float*)d_in[14]; const float* b1  = (const float*)d_in[15];
  const float* W2 = (const float*)d_in[16]; const float* b2  = (const float*)d_in[17];

  char* ws = (char*)d_ws;
  size_t off = 0;
  auto alloc = [&](size_t bytes) -> void* {
    void* p = ws + off;
    off += (bytes + 255) & ~(size_t)255;
    return p;
  };
  __bf16* xb   = (__bf16*)alloc((size_t)ROWS * EMBED * 2);
  __bf16* Wqt  = (__bf16*)alloc((size_t)EMBED * EMBED * 2);
  __bf16* Wkt  = (__bf16*)alloc((size_t)EMBED * EMBED * 2);
  __bf16* Wvt  = (__bf16*)alloc((size_t)EMBED * EMBED * 2);
  __bf16* Wot  = (__bf16*)alloc((size_t)EMBED * EMBED * 2);
  __bf16* W1t  = (__bf16*)alloc((size_t)EMBED * FFDIM * 2);
  __bf16* W2t  = (__bf16*)alloc((size_t)FFDIM * EMBED * 2);
  __bf16* Qb   = (__bf16*)alloc((size_t)ROWS * EMBED * 2);
  __bf16* Kb   = (__bf16*)alloc((size_t)ROWS * EMBED * 2);
  __bf16* Vtb  = (__bf16*)alloc((size_t)ROWS * EMBED * 2);
  __bf16* ctxb = (__bf16*)alloc((size_t)ROWS * EMBED * 2);
  __bf16* hb    = (__bf16*)alloc((size_t)ROWS * EMBED * 2);
  __bf16* a1    = (__bf16*)alloc((size_t)ROWS * FFDIM * 2);  // 32 MB
  int*   mflags = (int*)alloc(NB * 16 * 32 * sizeof(int));

  // f16 split-K partials: FF2 needs 4 planes x 8 MB = 32 MB
  const size_t pneed = (size_t)4 * ROWS * EMBED * sizeof(_Float16);
  int kspF2;
  _Float16* pF2;
  if (off + pneed <= ws_size) {
    pF2 = (_Float16*)alloc(pneed);
    kspF2 = 4;
  } else {
    pF2 = (_Float16*)Qb;  // Qb..ctxb dead once FF2 runs
    kspF2 = 2;
  }
  _Float16* pWo = (_Float16*)a1;  // a1 dead until FF1 (ln1 consumes partials first)

  // fused prologue: 3072 transpose + 1024 cast + 1024 mask-flag blocks
  prologue_k<<<5120, 256, 0, stream>>>(x, mask, Wq, Wk, Wv, Wo, W1, W2,
                                       xb, mflags, Wqt, Wkt, Wvt, Wot, W1t, W2t);

  // fused QKV (256^2, 16 waves): Q pre-scaled by log2e/2048
  gemm256<4><<<(ROWS / 256) * (3 * EMBED / 256), 1024, 0, stream>>>(
      xb, Wqt, bq, bk, bv, Qb, Kb, Vtb, ROWS, 3 * EMBED, EMBED, EMBED, LOG2E / 2048.0f);
  attn_k<<<NB * HEADS * (SLEN / 128), 512, 0, stream>>>(Qb, Kb, Vtb, mask, mflags, ctxb);
  // Wo projection (128^2 split-K x2, f16 partials); reduce fused into ln1
  gemm_bt5<<<(ROWS / 128) * (EMBED / 128) * 2, 256, 0, stream>>>(
      ctxb, Wot, pWo, ROWS, EMBED, EMBED, EMBED / 2);
  // ln1: residual = xb (bf16); writes only hb (bf16)
  ln_fused_k<<<ROWS, 256, 0, stream>>>(pWo, 2, bo, xb, g1, be1, nullptr, hb);
  // FF1 (256^2, 16 waves, relu epilogue)
  gemm256<3><<<(ROWS / 256) * (FFDIM / 256), 1024, 0, stream>>>(
      hb, W1t, b1, nullptr, nullptr, a1, nullptr, nullptr, ROWS, FFDIM, EMBED, EMBED, 1.0f);
  // FF2 (256^2, 16 waves, split-K x kspF2, f16 partials); reduce fused into ln2
  gemm256<5><<<(ROWS / 256) * (EMBED / 256) * kspF2, 1024, 0, stream>>>(
      a1, W2t, nullptr, nullptr, nullptr, pF2, nullptr, nullptr,
      ROWS, EMBED, FFDIM, FFDIM / kspF2, 1.0f);
  // ln2: residual = hb (bf16); writes f32 d_out
  ln_fused_k<<<ROWS, 256, 0, stream>>>(pF2, kspF2, b2, hb, g2, be2, (float*)d_out, nullptr);
}

// Round 19
// 260.096 us; speedup vs baseline: 1.2219x; 1.2219x over previous
//
#include <hip/hip_runtime.h>
#include <hip/hip_bf16.h>
#include <cstdint>
#include <cstddef>

#define EMBED 1024
#define SLEN  2048
#define NB    2
#define HEADS 16
#define HDIM  64
#define FFDIM 4096
#define ROWS  (NB * SLEN)   // 4096
#define LOG2E 1.4426950408889634f

typedef __attribute__((ext_vector_type(8))) __bf16 bf16x8;
typedef __attribute__((ext_vector_type(4))) __bf16 bf16x4;
typedef __attribute__((ext_vector_type(4))) float  f32x4;
typedef __attribute__((ext_vector_type(4))) _Float16 f16x4;

__device__ __forceinline__ void gload_lds16(const void* g, void* l) {
  __builtin_amdgcn_global_load_lds(
      (const __attribute__((address_space(1))) void*)g,
      (__attribute__((address_space(3))) void*)l, 16, 0, 0);
}

#define SCHED() __builtin_amdgcn_sched_barrier(0)
#define BAR()                              \
  do {                                     \
    __builtin_amdgcn_s_barrier();          \
    __builtin_amdgcn_sched_barrier(0);     \
  } while (0)
#define WAITVM(N)                                           \
  do {                                                      \
    asm volatile("s_waitcnt vmcnt(" #N ")" ::: "memory");   \
  } while (0)
#define WAITLGKM(N)                                         \
  do {                                                      \
    asm volatile("s_waitcnt lgkmcnt(" #N ")" ::: "memory"); \
  } while (0)

// ---- fused prologue: weight transposes (b<3072) + x cast (3072..4095) +
//      mask tile flags (4096..5119), one dispatch ----
__global__ __launch_bounds__(256) void prologue_k(
    const float* __restrict__ x, const int* __restrict__ mask,
    const float* __restrict__ Wq, const float* __restrict__ Wk,
    const float* __restrict__ Wv, const float* __restrict__ Wo,
    const float* __restrict__ W1, const float* __restrict__ W2,
    __bf16* __restrict__ xb, int* __restrict__ flags,
    __bf16* __restrict__ Wqt, __bf16* __restrict__ Wkt, __bf16* __restrict__ Wvt,
    __bf16* __restrict__ Wot, __bf16* __restrict__ W1t, __bf16* __restrict__ W2t) {
  const int b = blockIdx.x;
  const int tid = threadIdx.x;
  if (b < 3072) {  // ---- transpose+cast: in[R][C] f32 -> out[C][R] bf16 ----
    __shared__ float t[64][65];
    const float* src;
    __bf16* dst;
    int R, C, tile;
    if (b < 1024) {
      const int w = b >> 8;
      tile = b & 255; R = 1024; C = 1024;
      src = (w == 0) ? Wq : (w == 1) ? Wk : (w == 2) ? Wv : Wo;
      dst = (w == 0) ? Wqt : (w == 1) ? Wkt : (w == 2) ? Wvt : Wot;
    } else if (b < 2048) {
      tile = b - 1024; R = 1024; C = 4096; src = W1; dst = W1t;
    } else {
      tile = b - 2048; R = 4096; C = 1024; src = W2; dst = W2t;
    }
    const int ct = C >> 6;
    const int tr = (tile / ct) * 64, tc = (tile % ct) * 64;
    const int tx = tid & 63;
    const int ty = tid >> 6;
#pragma unroll
    for (int i = 0; i < 16; ++i) {
      int a = ty * 16 + i;
      t[a][tx] = src[(size_t)(tr + a) * C + tc + tx];
    }
    __syncthreads();
#pragma unroll
    for (int i = 0; i < 16; ++i) {
      int bb = ty * 16 + i;
      dst[(size_t)(tc + bb) * R + tr + tx] = (__bf16)t[tx][bb];
    }
  } else if (b < 4096) {  // ---- cast x: f32 -> bf16, 1024 float4/block ----
    const int base = (b - 3072) * 1024;
#pragma unroll
    for (int it = 0; it < 4; ++it) {
      const int i = base + it * 256 + tid;
      float4 v = ((const float4*)x)[i];
      bf16x4 o;
      o.x = (__bf16)v.x; o.y = (__bf16)v.y; o.z = (__bf16)v.z; o.w = (__bf16)v.w;
      ((bf16x4*)xb)[i] = o;
    }
  } else {  // ---- mask flags: 1 iff all mask!=0 in 128q x 64k tile ----
    const int mb = b - 4096;
    const int kt = mb & 31, qt = (mb >> 5) & 15, n = mb >> 9;
    const int* base = mask + ((size_t)n * SLEN + qt * 128) * SLEN + kt * 64;
    const int rw = tid >> 4;
    const int cg = tid & 15;
    int ok = 1;
#pragma unroll
    for (int i = 0; i < 8; ++i) {
      int4 v = ((const int4*)(base + (size_t)(rw + i * 16) * SLEN))[cg];
      ok &= (v.x != 0) & (v.y != 0) & (v.z != 0) & (v.w != 0);
    }
    __shared__ int red;
    if (tid == 0) red = 1;
    __syncthreads();
    if (!ok) red = 0;  // benign race: all writers store 0
    __syncthreads();
    if (tid == 0) flags[mb] = red;
  }
}

// ============ 256x256-tile GEMM, depth-4 fine-interleaved pipeline ==============
// 512 threads = 8 waves (2M x 4N). MODE 3: bf16 relu; MODE 4: fused QKV;
// MODE 5: split-K f16 partials.
template <int MODE>
__global__ __launch_bounds__(512, 1) void gemm256(
    const __bf16* __restrict__ A, const __bf16* __restrict__ Bt,
    const float* __restrict__ bias, const float* __restrict__ bias2,
    const float* __restrict__ bias3,
    void* __restrict__ outp, void* __restrict__ outp2, void* __restrict__ outp3,
    int M, int N, int K, int Kc, float oscale) {
  __shared__ __align__(16) char smem[131072];  // 4 x 32KB staging; epilogue aliases
  const int tid = threadIdx.x;
  const int lane = tid & 63;
  const int ntile = N >> 8;
  const int mt = M >> 8;
  const int cpx = gridDim.x >> 3;
  int u = (blockIdx.x & 7) * cpx + (blockIdx.x >> 3);  // XCD-chunked
  int kz = 0;
  if constexpr (MODE == 5) {
    const int tiles = mt * ntile;
    kz = u / tiles;
    u -= kz * tiles;
  }
  int bm, bn;
  {  // group-of-4 rasterization
    const int G = (ntile >= 4) ? 4 : ntile;
    const int gsz = mt * G;
    const int g = u / gsz;
    const int rem = u - g * gsz;
    bm = rem / G;
    bn = g * G + rem % G;
  }
  const int trow = bm << 8, tcol = bn << 8;

  const int r0 = tid & 255;
  const int c0 = tid >> 8;
  const __bf16* Ag = A + (size_t)(trow + r0) * K + (size_t)kz * Kc + c0 * 8;
  const __bf16* Bg = Bt + (size_t)(tcol + r0) * K + (size_t)kz * Kc + c0 * 8;

  auto stage = [&](int buf, int kt) {
    const __bf16* a0 = Ag + (size_t)kt * 32;
    const __bf16* b0 = Bg + (size_t)kt * 32;
    char* la = smem + buf * 32768 + tid * 16;
    char* lb = la + 16384;
    gload_lds16(a0, la);
    gload_lds16(a0 + 16, la + 8192);
    gload_lds16(b0, lb);
    gload_lds16(b0 + 16, lb + 8192);
  };

  const int wave = tid >> 6;
  const int wr = wave >> 2;
  const int wc = wave & 3;
  const int l16 = lane & 15;
  const int g4 = lane >> 4;

  f32x4 acc[8][4];
#pragma unroll
  for (int i = 0; i < 8; ++i)
#pragma unroll
    for (int j = 0; j < 4; ++j) acc[i][j] = (f32x4)0.0f;

  const int nk = Kc >> 5;
  stage(0, 0);
  stage(1, 1);
  stage(2, 2);
  WAITVM(8);  // tile 0 landed; 1,2 in flight
  BAR();
  for (int kt = 0; kt < nk; ++kt) {
    const int cur = kt & 3;
    const char* base = smem + cur * 32768;
    bf16x8 af[8], bfr[4];
#pragma unroll
    for (int i = 0; i < 4; ++i)
      af[i] = *(const bf16x8*)(base + g4 * 4096 + (wr * 128 + i * 16 + l16) * 16);
#pragma unroll
    for (int j = 0; j < 4; ++j)
      bfr[j] = *(const bf16x8*)(base + 16384 + g4 * 4096 + (wc * 64 + j * 16 + l16) * 16);
    SCHED();  // first 8 ds_reads pinned before the rest
#pragma unroll
    for (int i = 4; i < 8; ++i)
      af[i] = *(const bf16x8*)(base + g4 * 4096 + (wr * 128 + i * 16 + l16) * 16);
    if (kt + 3 < nk) stage((kt + 3) & 3, kt + 3);  // buffer dead since iter kt-1
    SCHED();
    WAITLGKM(4);  // af0-3 + bfr ready (af4-7 still outstanding)
    SCHED();
    __builtin_amdgcn_s_setprio(1);
#pragma unroll
    for (int mi = 0; mi < 4; ++mi)
#pragma unroll
      for (int ni = 0; ni < 4; ++ni)
        acc[mi][ni] =
            __builtin_amdgcn_mfma_f32_16x16x32_bf16(af[mi], bfr[ni], acc[mi][ni], 0, 0, 0);
    __builtin_amdgcn_s_setprio(0);
    SCHED();
    WAITLGKM(0);  // af4-7 ready (latency hidden under mi0-3 MFMA)
    SCHED();
    __builtin_amdgcn_s_setprio(1);
#pragma unroll
    for (int mi = 4; mi < 8; ++mi)
#pragma unroll
      for (int ni = 0; ni < 4; ++ni)
        acc[mi][ni] =
            __builtin_amdgcn_mfma_f32_16x16x32_bf16(af[mi], bfr[ni], acc[mi][ni], 0, 0, 0);
    __builtin_amdgcn_s_setprio(0);
    if (kt + 3 < nk) {
      WAITVM(8);   // tile kt+1 landed (own); barrier makes it all-waves
    } else if (kt + 3 == nk) {
      WAITVM(4);
    } else if (kt + 2 == nk) {
      WAITVM(0);
    }
    BAR();
  }

  if constexpr (MODE == 5) {
#pragma unroll
    for (int mi = 0; mi < 8; ++mi)
#pragma unroll
      for (int ni = 0; ni < 4; ++ni) {
        const int col = tcol + wc * 64 + ni * 16 + l16;
#pragma unroll
        for (int r = 0; r < 4; ++r) {
          const int row = trow + wr * 128 + mi * 16 + g4 * 4 + r;
          ((_Float16*)outp)[(size_t)kz * M * N + (size_t)row * N + col] =
              (_Float16)acc[mi][ni][r];
        }
      }
  } else {
    const int sel = (MODE == 4) ? (tcol >> 10) : 0;
    const float* bp = (MODE == 4) ? (sel == 0 ? bias : sel == 1 ? bias2 : bias3) : bias;
    const int cc0 = (MODE == 4) ? (tcol & 1023) : tcol;
    const int n = trow >> 11;
    if (MODE == 4 && sel == 2) {
      __bf16(*repT)[136] = (__bf16(*)[136])smem;
#pragma unroll
      for (int h = 0; h < 2; ++h) {
        __syncthreads();
        if (wr == h) {
#pragma unroll
          for (int mi = 0; mi < 8; ++mi)
#pragma unroll
            for (int ni = 0; ni < 4; ++ni) {
              const int cl = wc * 64 + ni * 16 + l16;
              const float bcol = bp[cc0 + cl];
#pragma unroll
              for (int r = 0; r < 4; ++r)
                repT[cl][mi * 16 + g4 * 4 + r] = (__bf16)(acc[mi][ni][r] + bcol);
            }
        }
        __syncthreads();
#pragma unroll
        for (int it = 0; it < 8; ++it) {
          const int cidx = it * 512 + tid;
          const int cl = cidx >> 4, seg = cidx & 15;
          const int col = cc0 + cl, hh = col >> 6, dd = col & 63;
          *(bf16x8*)((__bf16*)outp3 + ((size_t)((n * HEADS + hh) * HDIM) + dd) * SLEN +
                     (trow & 2047) + h * 128 + seg * 8) = *(const bf16x8*)&repT[cl][seg * 8];
        }
      }
    } else {
      __bf16(*rep)[264] = (__bf16(*)[264])smem;
#pragma unroll
      for (int h = 0; h < 2; ++h) {
        __syncthreads();
        if (wr == h) {
#pragma unroll
          for (int mi = 0; mi < 8; ++mi)
#pragma unroll
            for (int ni = 0; ni < 4; ++ni) {
              const int cl = wc * 64 + ni * 16 + l16;
              float bcol = bp[cc0 + cl];
#pragma unroll
              for (int r = 0; r < 4; ++r) {
                float v = acc[mi][ni][r] + bcol;
                if constexpr (MODE == 4) {
                  if (sel == 0) v *= oscale;
                } else {
                  v = fmaxf(v, 0.0f);
                }
                rep[mi * 16 + g4 * 4 + r][cl] = (__bf16)v;
              }
            }
        }
        __syncthreads();
        if constexpr (MODE == 3) {
#pragma unroll
          for (int it = 0; it < 8; ++it) {
            const int cidx = it * 512 + tid;
            const int rl = cidx >> 5, seg = cidx & 31;
            *(bf16x8*)((__bf16*)outp + (size_t)(trow + h * 128 + rl) * N + tcol + seg * 8) =
                *(const bf16x8*)&rep[rl][seg * 8];
          }
        } else {
          __bf16* dst = (sel == 0) ? (__bf16*)outp : (__bf16*)outp2;
#pragma unroll
          for (int it = 0; it < 8; ++it) {
            const int cidx = it * 512 + tid;
            const int rl = cidx >> 5, seg = cidx & 31;
            const int col = cc0 + seg * 8, hh = col >> 6, d = col & 63;
            const int s = (trow & 2047) + h * 128 + rl;
            *(bf16x8*)(dst + ((size_t)((n * HEADS + hh) * SLEN) + s) * HDIM + d) =
                *(const bf16x8*)&rep[rl][seg * 8];
          }
        }
      }
    }
  }
}

// ---------------- 128^2 GEMM (Wo split-K, f16 partials), depth-4 fine ----------------
__global__ __launch_bounds__(256, 2) void gemm_bt5(
    const __bf16* __restrict__ A, const __bf16* __restrict__ Bt,
    _Float16* __restrict__ outp, int M, int N, int K, int Kc) {
  __shared__ __align__(16) char smem[65536];  // 4 x 16KB
  const int tid = threadIdx.x;
  const int lane = tid & 63;
  const int ntile = N >> 7;
  const int cpx = gridDim.x >> 3;
  int u = (blockIdx.x & 7) * cpx + (blockIdx.x >> 3);
  const int tiles = (M >> 7) * ntile;
  const int kz = u / tiles;
  u -= kz * tiles;
  const int bm = u / ntile;
  const int bn = u % ntile;
  const int trow = bm << 7;
  const int tcol = bn << 7;

  const int c0 = tid >> 7;
  const int r0 = tid & 127;
  const __bf16* Ag = A + (size_t)(trow + r0) * K + (size_t)kz * Kc + c0 * 8;
  const __bf16* Bg = Bt + (size_t)(tcol + r0) * K + (size_t)kz * Kc + c0 * 8;

  auto stage = [&](int buf, int kt) {
    const __bf16* a0 = Ag + (size_t)kt * 32;
    const __bf16* b0 = Bg + (size_t)kt * 32;
    char* la = smem + buf * 16384 + tid * 16;
    char* lb = la + 8192;
    gload_lds16(a0, la);
    gload_lds16(a0 + 16, la + 4096);
    gload_lds16(b0, lb);
    gload_lds16(b0 + 16, lb + 4096);
  };

  const int wave = tid >> 6;
  const int wr = (wave >> 1) * 64;
  const int wc = (wave & 1) * 64;
  const int l16 = lane & 15;
  const int g4 = lane >> 4;

  f32x4 acc[4][4];
#pragma unroll
  for (int i = 0; i < 4; ++i)
#pragma unroll
    for (int j = 0; j < 4; ++j) acc[i][j] = (f32x4)0.0f;

  const int nk = Kc >> 5;
  stage(0, 0);
  stage(1, 1);
  stage(2, 2);
  WAITVM(8);
  BAR();
  for (int kt = 0; kt < nk; ++kt) {
    const int cur = kt & 3;
    const char* base = smem + cur * 16384;
    bf16x8 af[4], bfr[4];
#pragma unroll
    for (int i = 0; i < 4; ++i) {
      af[i]  = *(const bf16x8*)(base + g4 * 2048 + (wr + i * 16 + l16) * 16);
      bfr[i] = *(const bf16x8*)(base + 8192 + g4 * 2048 + (wc + i * 16 + l16) * 16);
    }
    if (kt + 3 < nk) stage((kt + 3) & 3, kt + 3);
    SCHED();
    WAITLGKM(0);
    SCHED();
    __builtin_amdgcn_s_setprio(1);
#pragma unroll
    for (int mi = 0; mi < 4; ++mi)
#pragma unroll
      for (int ni = 0; ni < 4; ++ni)
        acc[mi][ni] =
            __builtin_amdgcn_mfma_f32_16x16x32_bf16(af[mi], bfr[ni], acc[mi][ni], 0, 0, 0);
    __builtin_amdgcn_s_setprio(0);
    if (kt + 3 < nk) {
      WAITVM(8);
    } else if (kt + 3 == nk) {
      WAITVM(4);
    } else if (kt + 2 == nk) {
      WAITVM(0);
    }
    BAR();
  }
#pragma unroll
  for (int mi = 0; mi < 4; ++mi)
#pragma unroll
    for (int ni = 0; ni < 4; ++ni) {
      const int col = tcol + wc + ni * 16 + l16;
#pragma unroll
      for (int r = 0; r < 4; ++r) {
        const int row = trow + wr + mi * 16 + g4 * 4 + r;
        outp[(size_t)kz * M * N + (size_t)row * N + col] = (_Float16)acc[mi][ni][r];
      }
    }
}

// ---------------- flash attention: 8 waves x 16 q, LDS-staged K/V ----------------
// 512 blocks XCD-chunked; LDS 50 KB -> 2 blocks/CU = 16 waves/CU.
__global__ __launch_bounds__(512, 2) void attn_k(const __bf16* __restrict__ Q,
                                                 const __bf16* __restrict__ K,
                                                 const __bf16* __restrict__ Vt,
                                                 const int* __restrict__ mask,
                                                 const int* __restrict__ flags,
                                                 __bf16* __restrict__ ctx) {
  const int tid = threadIdx.x, lane = tid & 63, wave = tid >> 6;  // wave 0..7
  const int l16 = lane & 15, g4 = lane >> 4;
  const int bid = blockIdx.x;
  const int lb = (bid & 7) * 64 + (bid >> 3);
  const int qt = lb & 15, h = (lb >> 4) & 15, n = lb >> 8;
  const int q0 = qt * 128 + wave * 16;
  const __bf16* Qh = Q + (size_t)(n * HEADS + h) * SLEN * HDIM;
  const __bf16* Kh = K + (size_t)(n * HEADS + h) * SLEN * HDIM;
  const __bf16* Vh = Vt + (size_t)(n * HEADS + h) * HDIM * SLEN;
  const int* Mh = mask + (size_t)n * SLEN * SLEN;
  const int* Fh = flags + (n * 16 + qt) * 32;

  __shared__ __bf16 KV[2][2][8][64][8];              // 32 KB
  __shared__ __align__(16) __bf16 P_lds[8][16][72];  // 18 KB

  const int srow = tid & 63;
  const int schunk = tid >> 6;  // 0..7
  const __bf16* Kg = Kh + (size_t)srow * HDIM + schunk * 8;
  const __bf16* Vg = Vh + (size_t)srow * SLEN + schunk * 8;
  auto stage = [&](int buf, int kb) {
    char* lk = (char*)&KV[buf][0][0][0][0] + tid * 16;
    char* lv = (char*)&KV[buf][1][0][0][0] + tid * 16;
    gload_lds16(Kg + (size_t)kb * 64 * HDIM, lk);
    gload_lds16(Vg + kb * 64, lv);
  };

  const unsigned long long fbits = __ballot(Fh[lane & 31] != 0);

  bf16x8 qf[2];
#pragma unroll
  for (int kd = 0; kd < 2; ++kd)
    qf[kd] = *(const bf16x8*)(Qh + (size_t)(q0 + l16) * HDIM + kd * 32 + g4 * 8);

  float m_ = -INFINITY, lsum = 0.0f;
  f32x4 o[4];
#pragma unroll
  for (int ni = 0; ni < 4; ++ni) o[ni] = (f32x4)0.0f;

  const int nt = SLEN / 64;
  stage(0, 0);
  stage(1, 1);
  WAITVM(2);  // tile 0's 2 loads landed; tile 1 in flight
  BAR();
  int cur = 0;
  for (int kt = 0; kt < nt; ++kt) {
    const int kbase = kt * 64;
    const bool full = (fbits >> kt) & 1ull;
    bf16x8 kf[4][2], vf[2][4];
#pragma unroll
    for (int ni = 0; ni < 4; ++ni) {
      kf[ni][0] = *(const bf16x8*)&KV[cur][0][g4][ni * 16 + l16][0];
      kf[ni][1] = *(const bf16x8*)&KV[cur][0][4 + g4][ni * 16 + l16][0];
    }
    SCHED();
#pragma unroll
    for (int kb = 0; kb < 2; ++kb)
#pragma unroll
      for (int ni = 0; ni < 4; ++ni)
        vf[kb][ni] = *(const bf16x8*)&KV[cur][1][kb * 4 + g4][ni * 16 + l16][0];
    SCHED();
    WAITLGKM(8);  // kf ready; vf latency hides under QK + softmax
    SCHED();
    f32x4 s[4];
#pragma unroll
    for (int ni = 0; ni < 4; ++ni) s[ni] = (f32x4)0.0f;
    __builtin_amdgcn_s_setprio(1);
#pragma unroll
    for (int ni = 0; ni < 4; ++ni) {
      s[ni] = __builtin_amdgcn_mfma_f32_16x16x32_bf16(kf[ni][0], qf[0], s[ni], 0, 0, 0);
      s[ni] = __builtin_amdgcn_mfma_f32_16x16x32_bf16(kf[ni][1], qf[1], s[ni], 0, 0, 0);
    }
    __builtin_amdgcn_s_setprio(0);
    if (!full) {
#pragma unroll
      for (int ni = 0; ni < 4; ++ni)
#pragma unroll
        for (int r = 0; r < 4; ++r) {
          const int mk = Mh[(size_t)(q0 + l16) * SLEN + kbase + ni * 16 + 4 * g4 + r];
          s[ni][r] = mk ? s[ni][r] : -INFINITY;
        }
    }
    float a = fmaxf(fmaxf(s[0][0], s[0][1]), fmaxf(s[0][2], s[0][3]));
    float b = fmaxf(fmaxf(s[1][0], s[1][1]), fmaxf(s[1][2], s[1][3]));
    float c = fmaxf(fmaxf(s[2][0], s[2][1]), fmaxf(s[2][2], s[2][3]));
    float d = fmaxf(fmaxf(s[3][0], s[3][1]), fmaxf(s[3][2], s[3][3]));
    const float pmax = fmaxf(fmaxf(a, b), fmaxf(c, d));
    if (!__all(pmax <= m_ + 8.0f)) {  // rescale (first tile + rare growth)
      float pm2 = fmaxf(m_, pmax);
      pm2 = fmaxf(pm2, __shfl_xor(pm2, 16));
      pm2 = fmaxf(pm2, __shfl_xor(pm2, 32));
      const float al = __builtin_amdgcn_exp2f(m_ - pm2);
      m_ = pm2;
      lsum *= al;
#pragma unroll
      for (int r = 0; r < 4; ++r) {
        const float ao = __shfl(al, 4 * g4 + r);
#pragma unroll
        for (int ni = 0; ni < 4; ++ni) o[ni][r] *= ao;
      }
    }
    float ls = 0.0f;
#pragma unroll
    for (int ni = 0; ni < 4; ++ni) {
      bf16x4 pk;
#pragma unroll
      for (int r = 0; r < 4; ++r) {
        const float p = __builtin_amdgcn_exp2f(s[ni][r] - m_);
        ls += p;
        pk[r] = (__bf16)p;
      }
      *(bf16x4*)&P_lds[wave][l16][ni * 16 + 4 * g4] = pk;
    }
    lsum += ls;
    bf16x8 pa[2];
#pragma unroll
    for (int kb = 0; kb < 2; ++kb)
      pa[kb] = *(const bf16x8*)&P_lds[wave][l16][kb * 32 + 8 * g4];
    SCHED();
    WAITLGKM(0);
    SCHED();
    __builtin_amdgcn_s_setprio(1);
#pragma unroll
    for (int kb = 0; kb < 2; ++kb)
#pragma unroll
      for (int ni = 0; ni < 4; ++ni)
        o[ni] = __builtin_amdgcn_mfma_f32_16x16x32_bf16(pa[kb], vf[kb][ni], o[ni], 0, 0, 0);
    __builtin_amdgcn_s_setprio(0);
    WAITVM(0);  // tile kt+1 (staged last iter) landed
    BAR();      // all waves done reading KV[cur] and past their vm-wait
    if (kt + 2 < nt) stage(cur, kt + 2);  // overwrite just-freed buffer
    cur ^= 1;
  }
  {
    float l = lsum;
    l += __shfl_xor(l, 16);
    l += __shfl_xor(l, 32);
    lsum = l;
  }
#pragma unroll
  for (int r = 0; r < 4; ++r) {
    const float inv = __builtin_amdgcn_rcpf(__shfl(lsum, 4 * g4 + r));
#pragma unroll
    for (int ni = 0; ni < 4; ++ni) {
      ctx[((size_t)(n * SLEN) + q0 + 4 * g4 + r) * EMBED + h * HDIM + ni * 16 + l16] =
          (__bf16)(o[ni][r] * inv);
    }
  }
}

// ------- fused split-K reduce (f16 partials) + bias + bf16 residual + LayerNorm -------
// v = sum(p planes) + bias + (float)resb[row]; LN(v) -> of (f32, optional), ob (bf16, optional)
__global__ __launch_bounds__(256) void ln_fused_k(const _Float16* __restrict__ p, int nz,
                                                  const float* __restrict__ bias,
                                                  const __bf16* __restrict__ resb,
                                                  const float* __restrict__ gw,
                                                  const float* __restrict__ bw,
                                                  float* __restrict__ of,
                                                  __bf16* __restrict__ ob) {
  const int tid = threadIdx.x;
  const size_t row = blockIdx.x;
  float4 bb = ((const float4*)bias)[tid];
  bf16x4 rr = ((const bf16x4*)(resb + row * EMBED))[tid];
  float4 v;
  v.x = bb.x + (float)rr[0];
  v.y = bb.y + (float)rr[1];
  v.z = bb.z + (float)rr[2];
  v.w = bb.w + (float)rr[3];
  for (int z = 0; z < nz; ++z) {
    f16x4 pz = ((const f16x4*)(p + (size_t)z * ROWS * EMBED + row * EMBED))[tid];
    v.x += (float)pz[0]; v.y += (float)pz[1]; v.z += (float)pz[2]; v.w += (float)pz[3];
  }
  float s = v.x + v.y + v.z + v.w;
  float sq = v.x * v.x + v.y * v.y + v.z * v.z + v.w * v.w;
#pragma unroll
  for (int off = 1; off < 64; off <<= 1) {
    s += __shfl_xor(s, off);
    sq += __shfl_xor(sq, off);
  }
  __shared__ float red[8];
  if ((tid & 63) == 0) { red[tid >> 6] = s; red[4 + (tid >> 6)] = sq; }
  __syncthreads();
  s = red[0] + red[1] + red[2] + red[3];
  sq = red[4] + red[5] + red[6] + red[7];
  const float mean = s * (1.0f / EMBED);
  const float var = sq * (1.0f / EMBED) - mean * mean;
  const float rstd = rsqrtf(var + 1e-5f);
  float4 gv = ((const float4*)gw)[tid];
  float4 bv2 = ((const float4*)bw)[tid];
  float4 ov;
  ov.x = (v.x - mean) * rstd * gv.x + bv2.x;
  ov.y = (v.y - mean) * rstd * gv.y + bv2.y;
  ov.z = (v.z - mean) * rstd * gv.z + bv2.z;
  ov.w = (v.w - mean) * rstd * gv.w + bv2.w;
  if (of) ((float4*)(of + row * EMBED))[tid] = ov;
  if (ob) {
    bf16x4 oh;
    oh.x = (__bf16)ov.x; oh.y = (__bf16)ov.y; oh.z = (__bf16)ov.z; oh.w = (__bf16)ov.w;
    ((bf16x4*)(ob + row * EMBED))[tid] = oh;
  }
}

extern "C" void kernel_launch(void* const* d_in, const int* in_sizes, int n_in,
                              void* d_out, int out_size, void* d_ws, size_t ws_size,
                              hipStream_t stream) {
  (void)in_sizes; (void)n_in; (void)out_size;
  const float* x   = (const float*)d_in[0];
  const int*  mask = (const int*)d_in[1];
  const float* Wq = (const float*)d_in[2];  const float* bq  = (const float*)d_in[3];
  const float* Wk = (const float*)d_in[4];  const float* bk  = (const float*)d_in[5];
  const float* Wv = (const float*)d_in[6];  const float* bv  = (const float*)d_in[7];
  const float* Wo = (const float*)d_in[8];  const float* bo  = (const float*)d_in[9];
  const float* g1 = (const float*)d_in[10]; const float* be1 = (const float*)d_in[11];
  const float* g2 = (const float*)d_in[12]; const float* be2 = (const float*)d_in[13];
  const float* W1 = (const float*)d_in[14]; const float* b1  = (const float*)d_in[15];
  const float* W2 = (const float*)d_in[16]; const float* b2  = (const float*)d_in[17];

  char* ws = (char*)d_ws;
  size_t off = 0;
  auto alloc = [&](size_t bytes) -> void* {
    void* p = ws + off;
    off += (bytes + 255) & ~(size_t)255;
    return p;
  };
  __bf16* xb   = (__bf16*)alloc((size_t)ROWS * EMBED * 2);
  __bf16* Wqt  = (__bf16*)alloc((size_t)EMBED * EMBED * 2);
  __bf16* Wkt  = (__bf16*)alloc((size_t)EMBED * EMBED * 2);
  __bf16* Wvt  = (__bf16*)alloc((size_t)EMBED * EMBED * 2);
  __bf16* Wot  = (__bf16*)alloc((size_t)EMBED * EMBED * 2);
  __bf16* W1t  = (__bf16*)alloc((size_t)EMBED * FFDIM * 2);
  __bf16* W2t  = (__bf16*)alloc((size_t)FFDIM * EMBED * 2);
  __bf16* Qb   = (__bf16*)alloc((size_t)ROWS * EMBED * 2);
  __bf16* Kb   = (__bf16*)alloc((size_t)ROWS * EMBED * 2);
  __bf16* Vtb  = (__bf16*)alloc((size_t)ROWS * EMBED * 2);
  __bf16* ctxb = (__bf16*)alloc((size_t)ROWS * EMBED * 2);
  __bf16* hb    = (__bf16*)alloc((size_t)ROWS * EMBED * 2);
  __bf16* a1    = (__bf16*)alloc((size_t)ROWS * FFDIM * 2);  // 32 MB
  int*   mflags = (int*)alloc(NB * 16 * 32 * sizeof(int));

  // f16 split-K partials: FF2 needs 4 planes x 8 MB = 32 MB
  const size_t pneed = (size_t)4 * ROWS * EMBED * sizeof(_Float16);
  int kspF2;
  _Float16* pF2;
  if (off + pneed <= ws_size) {
    pF2 = (_Float16*)alloc(pneed);
    kspF2 = 4;
  } else {
    pF2 = (_Float16*)Qb;  // Qb..ctxb dead once FF2 runs
    kspF2 = 2;
  }
  _Float16* pWo = (_Float16*)a1;  // a1 dead until FF1 (ln1 consumes partials first)

  // fused prologue: 3072 transpose + 1024 cast + 1024 mask-flag blocks
  prologue_k<<<5120, 256, 0, stream>>>(x, mask, Wq, Wk, Wv, Wo, W1, W2,
                                       xb, mflags, Wqt, Wkt, Wvt, Wot, W1t, W2t);

  // fused QKV (256^2, depth-4 fine pipeline): Q pre-scaled by log2e/2048
  gemm256<4><<<(ROWS / 256) * (3 * EMBED / 256), 512, 0, stream>>>(
      xb, Wqt, bq, bk, bv, Qb, Kb, Vtb, ROWS, 3 * EMBED, EMBED, EMBED, LOG2E / 2048.0f);
  attn_k<<<NB * HEADS * (SLEN / 128), 512, 0, stream>>>(Qb, Kb, Vtb, mask, mflags, ctxb);
  // Wo projection (128^2 split-K x2, f16 partials); reduce fused into ln1
  gemm_bt5<<<(ROWS / 128) * (EMBED / 128) * 2, 256, 0, stream>>>(
      ctxb, Wot, pWo, ROWS, EMBED, EMBED, EMBED / 2);
  // ln1: residual = xb (bf16); writes only hb (bf16)
  ln_fused_k<<<ROWS, 256, 0, stream>>>(pWo, 2, bo, xb, g1, be1, nullptr, hb);
  // FF1 (256^2, relu epilogue)
  gemm256<3><<<(ROWS / 256) * (FFDIM / 256), 512, 0, stream>>>(
      hb, W1t, b1, nullptr, nullptr, a1, nullptr, nullptr, ROWS, FFDIM, EMBED, EMBED, 1.0f);
  // FF2 (256^2, split-K x kspF2, f16 partials); reduce fused into ln2
  gemm256<5><<<(ROWS / 256) * (EMBED / 256) * kspF2, 512, 0, stream>>>(
      a1, W2t, nullptr, nullptr, nullptr, pF2, nullptr, nullptr,
      ROWS, EMBED, FFDIM, FFDIM / kspF2, 1.0f);
  // ln2: residual = hb (bf16); writes f32 d_out
  ln_fused_k<<<ROWS, 256, 0, stream>>>(pF2, kspF2, b2, hb, g2, be2, (float*)d_out, nullptr);
}